// Round 2
// baseline (53.121 us; speedup 1.0000x reference)
//
#include <hip/hip_runtime.h>
#include <hip/hip_bf16.h>

// Problem constants (B=16, N=1024, DIN=128, DH=256)
#define NB     16
#define NN     1024
#define NP1    1025          // N+1
#define DIN    128
#define DH     256

#define OFF0   0                           // input_X: 16*1025*128 = 2099200
#define OFF1   2099200                     // input_MASK: 16*1025 = 16400
#define OFF2   2115600                     // bias_mat: 16*1025*1025 = 16810000

#define NB_BIAS  (NB * NP1)                // 16400 blocks: one bias row each
#define NB_COPY  (NB * 16)                 // 256 blocks: feature copy
#define NB_MASK  NB                        // 16 blocks: mask rows

// ---------------- Kernel 1: tiny MLP -> 7-entry LUT in d_ws -----------------
__global__ __launch_bounds__(256) void lut_kernel(
    const float* __restrict__ cb,   // (6,128)
    const float* __restrict__ W1,   // (128,256)
    const float* __restrict__ b1,   // (256,)
    const float* __restrict__ W2,   // (256,1)
    const float* __restrict__ b2,   // (1,)
    float* __restrict__ lut)        // (7,)
{
    const int t = threadIdx.x;      // 0..255, t indexes DH
    __shared__ float part[4];
    for (int c = 0; c < 6; ++c) {
        const float* cbr = cb + c * DIN;
        float acc = 0.f;
        #pragma unroll 8
        for (int k = 0; k < DIN; ++k)
            acc = fmaf(cbr[k], W1[k * DH + t], acc);
        float h = fmaxf(acc + b1[t], 0.f);
        float p = h * W2[t];
        // wave-64 reduce
        #pragma unroll
        for (int off = 32; off; off >>= 1)
            p += __shfl_down(p, off);
        if ((t & 63) == 0) part[t >> 6] = p;
        __syncthreads();
        if (t == 0) lut[c] = part[0] + part[1] + part[2] + part[3] + b2[0];
        __syncthreads();
    }
    if (t == 0) lut[6] = 0.f;
}

// ---------------- Kernel 2: everything else ---------------------------------
__global__ __launch_bounds__(256) void main_kernel(
    const float* __restrict__ feat,          // (16,1024,128)
    const int* __restrict__ mask,            // (16,1024) bool -> int32
    const int* __restrict__ dm,              // (16,1024,1024)
    const float* __restrict__ tst,           // (1,1,128)
    const float* __restrict__ lut,           // (7,) in d_ws
    float* __restrict__ out)
{
    const int bid = blockIdx.x;
    const int tid = threadIdx.x;

    if (bid < NB_BIAS) {
        // -------- one bias_mat row --------
        __shared__ float sl[7];
        if (tid < 7) sl[tid] = lut[tid];
        __syncthreads();

        const int b = bid / NP1;
        const int i = bid - b * NP1;
        float* __restrict__ orow = out + OFF2 + (size_t)bid * NP1;
        const int* __restrict__ dmb = dm + (size_t)b * (NN * NN);

        if (i == 0) {
            // D[b,0,0] = 0 -> sel 0
            if (tid == 0) orow[0] = sl[0];
            // D[b,0,1+j] = upd[j], upd from dm row 0
            for (int j = 1 + tid; j < NP1; j += 256) {
                int r = dmb[j - 1];
                orow[j] = (r <= 3) ? sl[r + 1] : (r == 9999 ? sl[5] : sl[6]);
            }
        } else {
            if (tid == 0) {
                int r = dmb[i - 1];              // dm[b,0,i-1] -> upd -> col 0
                orow[0] = (r <= 3) ? sl[r + 1] : (r == 9999 ? sl[5] : sl[6]);
            }
            const int* __restrict__ dr = dmb + (size_t)(i - 1) * NN;
            // 4-deep ILP, fully coalesced scalar traffic
            int d0 = dr[tid];
            int d1 = dr[tid + 256];
            int d2 = dr[tid + 512];
            int d3 = dr[tid + 768];
            orow[1 + tid]       = (d0 == 9999) ? sl[5] : (d0 < 5 ? sl[d0] : sl[6]);
            orow[1 + tid + 256] = (d1 == 9999) ? sl[5] : (d1 < 5 ? sl[d1] : sl[6]);
            orow[1 + tid + 512] = (d2 == 9999) ? sl[5] : (d2 < 5 ? sl[d2] : sl[6]);
            orow[1 + tid + 768] = (d3 == 9999) ? sl[5] : (d3 < 5 ? sl[d3] : sl[6]);
        }
    } else if (bid < NB_BIAS + NB_COPY) {
        // -------- input_X copy (float4) --------
        const int cid  = bid - NB_BIAS;
        const int b    = cid >> 4;       // 16 chunks per batch
        const int chnk = cid & 15;
        // per-batch: 1024*128 = 131072 floats = 32768 float4; 2048 float4/chunk
        const float4* __restrict__ src =
            (const float4*)(feat + (size_t)b * (NN * DIN)) + (size_t)chnk * 2048;
        float4* __restrict__ dst =
            (float4*)(out + (size_t)b * (NP1 * DIN) + DIN) + (size_t)chnk * 2048;
        #pragma unroll
        for (int u = 0; u < 8; ++u)
            dst[tid + 256 * u] = src[tid + 256 * u];
        if (chnk == 0 && tid < 32) {
            // tst_token row (128 floats = 32 float4)
            ((float4*)(out + (size_t)b * (NP1 * DIN)))[tid] =
                ((const float4*)tst)[tid];
        }
    } else {
        // -------- input_MASK row --------
        const int b = bid - (NB_BIAS + NB_COPY);
        float* __restrict__ om = out + OFF1 + b * NP1;
        const int* __restrict__ mb = mask + (size_t)b * NN;
        if (tid == 0) om[0] = 1.0f;
        for (int j = tid; j < NN; j += 256)
            om[1 + j] = mb[j] ? 1.0f : 0.0f;
    }
}

extern "C" void kernel_launch(void* const* d_in, const int* in_sizes, int n_in,
                              void* d_out, int out_size, void* d_ws, size_t ws_size,
                              hipStream_t stream) {
    const float* feat = (const float*)d_in[0];
    const int*   mask = (const int*)d_in[1];
    const int*   dm   = (const int*)d_in[2];
    const float* tst  = (const float*)d_in[3];
    const float* cb   = (const float*)d_in[4];
    const float* W1   = (const float*)d_in[5];
    const float* b1   = (const float*)d_in[6];
    const float* W2   = (const float*)d_in[7];
    const float* b2   = (const float*)d_in[8];
    float* out = (float*)d_out;
    float* lut = (float*)d_ws;

    lut_kernel<<<1, 256, 0, stream>>>(cb, W1, b1, W2, b2, lut);
    main_kernel<<<NB_BIAS + NB_COPY + NB_MASK, 256, 0, stream>>>(
        feat, mask, dm, tst, lut, out);
}

// Round 3
// 34.334 us; speedup vs baseline: 1.5472x; 1.5472x over previous
//
#include <hip/hip_runtime.h>
#include <hip/hip_bf16.h>

// Problem constants (B=16, N=1024, DIN=128, DH=256)
#define NB     16
#define NN     1024
#define NP1    1025          // N+1
#define DIN    128
#define DH     256

#define OFF1   2099200                     // input_MASK offset (floats)
#define OFF2   2115600                     // bias_mat offset (floats)

#define ROWS_PER_BLK 4
#define NB_BIAS  (NB * NP1 / ROWS_PER_BLK)  // 4100 blocks, 4 bias rows each
#define NB_COPY  (NB * 16)                  // 256 blocks: feature copy
#define NB_MASK  NB                         // 16 blocks: mask rows

// ---------------- Kernel 1: tiny MLP -> 7-entry LUT in d_ws -----------------
// 6 blocks, one codebook row each (parallel, short dependent chains).
__global__ __launch_bounds__(256) void lut_kernel(
    const float* __restrict__ cb,   // (6,128)
    const float* __restrict__ W1,   // (128,256)
    const float* __restrict__ b1,   // (256,)
    const float* __restrict__ W2,   // (256,1)
    const float* __restrict__ b2,   // (1,)
    float* __restrict__ lut)        // (7,)
{
    const int c = blockIdx.x;       // 0..5
    const int t = threadIdx.x;      // 0..255 = hidden unit
    const float* __restrict__ cbr = cb + c * DIN;
    float acc = 0.f;
    #pragma unroll
    for (int k = 0; k < DIN; k += 8) {
        float a0 = W1[(k + 0) * DH + t];
        float a1 = W1[(k + 1) * DH + t];
        float a2 = W1[(k + 2) * DH + t];
        float a3 = W1[(k + 3) * DH + t];
        float a4 = W1[(k + 4) * DH + t];
        float a5 = W1[(k + 5) * DH + t];
        float a6 = W1[(k + 6) * DH + t];
        float a7 = W1[(k + 7) * DH + t];
        acc = fmaf(cbr[k + 0], a0, acc);
        acc = fmaf(cbr[k + 1], a1, acc);
        acc = fmaf(cbr[k + 2], a2, acc);
        acc = fmaf(cbr[k + 3], a3, acc);
        acc = fmaf(cbr[k + 4], a4, acc);
        acc = fmaf(cbr[k + 5], a5, acc);
        acc = fmaf(cbr[k + 6], a6, acc);
        acc = fmaf(cbr[k + 7], a7, acc);
    }
    float h = fmaxf(acc + b1[t], 0.f);
    float p = h * W2[t];
    #pragma unroll
    for (int off = 32; off; off >>= 1)
        p += __shfl_down(p, off);
    __shared__ float part[4];
    if ((t & 63) == 0) part[t >> 6] = p;
    __syncthreads();
    if (t == 0) {
        lut[c] = part[0] + part[1] + part[2] + part[3] + b2[0];
        if (c == 0) lut[6] = 0.f;
    }
}

// ---------------- Kernel 2: everything else ---------------------------------
__global__ __launch_bounds__(256) void main_kernel(
    const float* __restrict__ feat,          // (16,1024,128)
    const int* __restrict__ mask,            // (16,1024) bool -> int32
    const int* __restrict__ dm,              // (16,1024,1024)
    const float* __restrict__ tst,           // (1,1,128)
    const float* __restrict__ lut,           // (7,) in d_ws
    float* __restrict__ out)
{
    const int bid = blockIdx.x;
    const int tid = threadIdx.x;

    if (bid < NB_BIAS) {
        // -------- ROWS_PER_BLK consecutive flat bias rows --------
        __shared__ float sl[7];
        if (tid < 7) sl[tid] = lut[tid];
        __syncthreads();

        const int g0 = bid * ROWS_PER_BLK;   // flat row index in [0, 16400)
        #pragma unroll
        for (int k = 0; k < ROWS_PER_BLK; ++k) {
            const int g = g0 + k;
            const int b = g / NP1;           // magic-mul
            const int i = g - b * NP1;
            float* __restrict__ orow = out + OFF2 + (size_t)g * NP1;
            const int* __restrict__ dmb = dm + (size_t)b * (NN * NN);

            if (i == 0) {
                // row 0: D[0,0]=0 ; D[0,1+j] = upd(dm[b,0,j])
                if (tid == 0) orow[0] = sl[0];
                int r0 = dmb[tid];
                int r1 = dmb[tid + 256];
                int r2 = dmb[tid + 512];
                int r3 = dmb[tid + 768];
                orow[1 + tid]       = (r0 == 9999) ? sl[5] : (r0 <= 3 ? sl[r0 + 1] : sl[6]);
                orow[1 + tid + 256] = (r1 == 9999) ? sl[5] : (r1 <= 3 ? sl[r1 + 1] : sl[6]);
                orow[1 + tid + 512] = (r2 == 9999) ? sl[5] : (r2 <= 3 ? sl[r2 + 1] : sl[6]);
                orow[1 + tid + 768] = (r3 == 9999) ? sl[5] : (r3 <= 3 ? sl[r3 + 1] : sl[6]);
            } else {
                if (tid == 0) {
                    int r = dmb[i - 1];      // upd(dm[b,0,i-1]) -> col 0
                    orow[0] = (r == 9999) ? sl[5] : (r <= 3 ? sl[r + 1] : sl[6]);
                }
                const int* __restrict__ dr = dmb + (size_t)(i - 1) * NN;
                int d0 = dr[tid];
                int d1 = dr[tid + 256];
                int d2 = dr[tid + 512];
                int d3 = dr[tid + 768];
                orow[1 + tid]       = (d0 == 9999) ? sl[5] : (d0 < 5 ? sl[d0] : sl[6]);
                orow[1 + tid + 256] = (d1 == 9999) ? sl[5] : (d1 < 5 ? sl[d1] : sl[6]);
                orow[1 + tid + 512] = (d2 == 9999) ? sl[5] : (d2 < 5 ? sl[d2] : sl[6]);
                orow[1 + tid + 768] = (d3 == 9999) ? sl[5] : (d3 < 5 ? sl[d3] : sl[6]);
            }
        }
    } else if (bid < NB_BIAS + NB_COPY) {
        // -------- input_X copy (float4) --------
        const int cid  = bid - NB_BIAS;
        const int b    = cid >> 4;
        const int chnk = cid & 15;
        const float4* __restrict__ src =
            (const float4*)(feat + (size_t)b * (NN * DIN)) + (size_t)chnk * 2048;
        float4* __restrict__ dst =
            (float4*)(out + (size_t)b * (NP1 * DIN) + DIN) + (size_t)chnk * 2048;
        #pragma unroll
        for (int u = 0; u < 8; ++u)
            dst[tid + 256 * u] = src[tid + 256 * u];
        if (chnk == 0 && tid < 32) {
            ((float4*)(out + (size_t)b * (NP1 * DIN)))[tid] =
                ((const float4*)tst)[tid];
        }
    } else {
        // -------- input_MASK row --------
        const int b = bid - (NB_BIAS + NB_COPY);
        float* __restrict__ om = out + OFF1 + b * NP1;
        const int* __restrict__ mb = mask + (size_t)b * NN;
        if (tid == 0) om[0] = 1.0f;
        for (int j = tid; j < NN; j += 256)
            om[1 + j] = mb[j] ? 1.0f : 0.0f;
    }
}

extern "C" void kernel_launch(void* const* d_in, const int* in_sizes, int n_in,
                              void* d_out, int out_size, void* d_ws, size_t ws_size,
                              hipStream_t stream) {
    const float* feat = (const float*)d_in[0];
    const int*   mask = (const int*)d_in[1];
    const int*   dm   = (const int*)d_in[2];
    const float* tst  = (const float*)d_in[3];
    const float* cb   = (const float*)d_in[4];
    const float* W1   = (const float*)d_in[5];
    const float* b1   = (const float*)d_in[6];
    const float* W2   = (const float*)d_in[7];
    const float* b2   = (const float*)d_in[8];
    float* out = (float*)d_out;
    float* lut = (float*)d_ws;

    lut_kernel<<<6, 256, 0, stream>>>(cb, W1, b1, W2, b2, lut);
    main_kernel<<<NB_BIAS + NB_COPY + NB_MASK, 256, 0, stream>>>(
        feat, mask, dm, tst, lut, out);
}